// Round 1
// baseline (3681.225 us; speedup 1.0000x reference)
//
#include <hip/hip_runtime.h>
#include <hip/hip_bf16.h>

#define N_PTS 8192
#define N_SAMP 2048
#define KNN_K 16
#define NBATCH 4
#define BN_M (NBATCH * N_SAMP * KNN_K)  // 131072

// ---------------------------------------------------------------- FPS
// One block per batch. xyz staged in LDS (broadcast + final gather); each
// thread's 8 points live in registers. Packed u64 argmax: (f32bits<<32)|~idx
// so max => farthest point, ties => smallest index (matches jnp.argmax).
__global__ __launch_bounds__(1024) void fps_kernel(const float* __restrict__ xyz,
                                                   int* __restrict__ fps_idx,
                                                   float* __restrict__ new_xyz) {
  __shared__ float xs[N_PTS], ys[N_PTS], zs[N_PTS];
  __shared__ int samp[N_SAMP];
  __shared__ unsigned long long red[17];
  const int b = blockIdx.x;
  const int tid = threadIdx.x;
  const int lane = tid & 63;
  const int wid = tid >> 6;
  const float* base = xyz + (size_t)b * N_PTS * 3;
  for (int i = tid; i < N_PTS * 3; i += 1024) {
    float v = base[i];
    int p = i / 3, c = i - p * 3;
    if (c == 0) xs[p] = v; else if (c == 1) ys[p] = v; else zs[p] = v;
  }
  if (tid == 0) samp[0] = 0;
  __syncthreads();

  float px[8], py[8], pz[8], dmin[8];
#pragma unroll
  for (int j = 0; j < 8; ++j) {
    int p = j * 1024 + tid;
    px[j] = xs[p]; py[j] = ys[p]; pz[j] = zs[p];
    dmin[j] = 1e10f;
  }
  int cur = 0;
  for (int it = 1; it < N_SAMP; ++it) {
    float cx = xs[cur], cy = ys[cur], cz = zs[cur];
    float bestd = -1.0f; int bestp = 0;
#pragma unroll
    for (int j = 0; j < 8; ++j) {
      // match XLA: sub, square, left-assoc add reduce; NO fma contraction
      float dx = __fsub_rn(px[j], cx);
      float dy = __fsub_rn(py[j], cy);
      float dz = __fsub_rn(pz[j], cz);
      float d = __fadd_rn(__fadd_rn(__fmul_rn(dx, dx), __fmul_rn(dy, dy)), __fmul_rn(dz, dz));
      dmin[j] = fminf(dmin[j], d);
      if (dmin[j] > bestd) { bestd = dmin[j]; bestp = j * 1024 + tid; }
    }
    unsigned long long key =
        ((unsigned long long)__float_as_uint(bestd) << 32) | (unsigned)(~bestp);
#pragma unroll
    for (int o = 32; o > 0; o >>= 1) {
      unsigned long long other = __shfl_xor(key, o, 64);
      key = (other > key) ? other : key;
    }
    if (lane == 0) red[wid] = key;
    __syncthreads();
    if (wid == 0) {
      unsigned long long k2 = red[lane & 15];
#pragma unroll
      for (int o = 8; o > 0; o >>= 1) {
        unsigned long long other = __shfl_xor(k2, o, 64);
        k2 = (other > k2) ? other : k2;
      }
      if (lane == 0) {
        red[16] = k2;
        samp[it] = (int)(~(unsigned)k2);
      }
    }
    __syncthreads();
    cur = (int)(~(unsigned)red[16]);
  }
  __syncthreads();
  for (int s = tid; s < N_SAMP; s += 1024) {
    int idx = samp[s];
    fps_idx[b * N_SAMP + s] = idx;
    size_t o = ((size_t)b * N_SAMP + s) * 3;
    new_xyz[o] = xs[idx]; new_xyz[o + 1] = ys[idx]; new_xyz[o + 2] = zs[idx];
  }
}

// ---------------------------------------------------------------- kNN
// One wave per query. Per-lane sorted top-16 (packed u64), 16-round
// wave-min merge. d = (qn+pn) - 2*dot, dot as fma chain (Eigen-gemm style).
__global__ __launch_bounds__(256) void knn_kernel(const float* __restrict__ xyz,
                                                  const float* __restrict__ new_xyz,
                                                  int* __restrict__ knn_idx) {
  const int wid = threadIdx.x >> 6, lane = threadIdx.x & 63;
  const int q = blockIdx.x * 4 + wid;
  const int b = q >> 11;
  const float* qp = new_xyz + (size_t)q * 3;
  float q0 = qp[0], q1 = qp[1], q2 = qp[2];
  float qn = __fadd_rn(__fadd_rn(__fmul_rn(q0, q0), __fmul_rn(q1, q1)), __fmul_rn(q2, q2));
  const float* pb = xyz + (size_t)b * N_PTS * 3;
  unsigned long long arr[16];
#pragma unroll
  for (int i = 0; i < 16; ++i) arr[i] = ~0ull;
  for (int p = lane; p < N_PTS; p += 64) {
    float p0 = pb[p * 3 + 0], p1 = pb[p * 3 + 1], p2 = pb[p * 3 + 2];
    float pn = __fadd_rn(__fadd_rn(__fmul_rn(p0, p0), __fmul_rn(p1, p1)), __fmul_rn(p2, p2));
    float dt = fmaf(q2, p2, fmaf(q1, p1, __fmul_rn(q0, p0)));
    float d = __fsub_rn(__fadd_rn(qn, pn), __fmul_rn(2.0f, dt));
    unsigned ub = __float_as_uint(d);
    ub ^= (unsigned)((int)ub >> 31) | 0x80000000u;  // order-preserving map (handles d<0)
    unsigned long long key = ((unsigned long long)ub << 32) | (unsigned)p;
    if (key < arr[15]) {
      unsigned long long curk = key;
#pragma unroll
      for (int j = 0; j < 16; ++j) {
        unsigned long long lo = (curk < arr[j]) ? curk : arr[j];
        unsigned long long hi = (curk < arr[j]) ? arr[j] : curk;
        arr[j] = lo; curk = hi;
      }
    }
  }
  for (int r = 0; r < KNN_K; ++r) {
    unsigned long long m = arr[0];
#pragma unroll
    for (int o = 32; o > 0; o >>= 1) {
      unsigned long long other = __shfl_xor(m, o, 64);
      m = (other < m) ? other : m;
    }
    if (arr[0] == m) {  // unique winner (idx in low bits)
#pragma unroll
      for (int j = 0; j < 15; ++j) arr[j] = arr[j + 1];
      arr[15] = ~0ull;
    }
    if (lane == r) knn_idx[(size_t)q * KNN_K + r] = (int)(m & 0xFFFFFFFFu);
  }
}

// ---------------------------------------------------------------- MLP passes
// PASS 0: mm1 -> stats1.  PASS 1: mm1->BN1->relu->mm2 -> stats2.
// PASS 2: full chain -> BN2 -> relu -> max over K -> out.
// Block = one (b,s): 16 rows (K) x 128 ch; thread (k, cg) owns 8 channels.
template <int PASS>
__global__ __launch_bounds__(256) void mlp_kernel(
    const float* __restrict__ xyz, const float* __restrict__ feat,
    const float* __restrict__ W1, const float* __restrict__ g1v, const float* __restrict__ b1v,
    const float* __restrict__ W2, const float* __restrict__ g2v, const float* __restrict__ b2v,
    const float* __restrict__ new_xyz, const int* __restrict__ knn_idx,
    float* __restrict__ stats1, float* __restrict__ stats2,
    float* __restrict__ out_feat) {
  constexpr int BUFA = (PASS == 0) ? (67 * 128) : (128 * 128);
  constexpr int ZR = (PASS == 0) ? 1 : 16;
  __shared__ __align__(16) float bufA[BUFA];     // W1, then (PASS>=1) W2
  __shared__ float xrow[16][68];
  __shared__ float zS[ZR][132];
  __shared__ float spart[4][16][16];
  __shared__ int nidx[16];
  __shared__ float qv[3];
  const int tid = threadIdx.x;
  const int bs = blockIdx.x;
  const int b = bs >> 11;
  const int lane = tid & 63, w = tid >> 6;
  const int k = tid >> 4, cg = tid & 15;
  const float inv_m = 1.0f / (float)BN_M;

  if (tid < 16) nidx[tid] = knn_idx[(size_t)bs * KNN_K + tid];
  if (tid >= 32 && tid < 35) qv[tid - 32] = new_xyz[(size_t)bs * 3 + (tid - 32)];
  for (int i = tid; i < 67 * 128; i += 256) bufA[i] = W1[i];
  __syncthreads();
  for (int i = tid; i < 16 * 64; i += 256) {
    int kk = i >> 6, c = i & 63;
    xrow[kk][c] = feat[((size_t)b * N_PTS + nidx[kk]) * 64 + c];
  }
  if (tid < 48) {
    int kk = tid / 3, c = tid - kk * 3;
    xrow[kk][64 + c] = __fsub_rn(xyz[((size_t)b * N_PTS + nidx[kk]) * 3 + c], qv[c]);
  }
  __syncthreads();

  float acc[8];
#pragma unroll
  for (int i = 0; i < 8; ++i) acc[i] = 0.f;
  for (int j = 0; j < 67; ++j) {
    float xv = xrow[k][j];
    const float4* wp = reinterpret_cast<const float4*>(&bufA[j * 128 + cg * 8]);
    float4 wa = wp[0], wb = wp[1];
    acc[0] = fmaf(xv, wa.x, acc[0]); acc[1] = fmaf(xv, wa.y, acc[1]);
    acc[2] = fmaf(xv, wa.z, acc[2]); acc[3] = fmaf(xv, wa.w, acc[3]);
    acc[4] = fmaf(xv, wb.x, acc[4]); acc[5] = fmaf(xv, wb.y, acc[5]);
    acc[6] = fmaf(xv, wb.z, acc[6]); acc[7] = fmaf(xv, wb.w, acc[7]);
  }

  if constexpr (PASS == 0) {
    float sq[8];
#pragma unroll
    for (int i = 0; i < 8; ++i) sq[i] = acc[i] * acc[i];
#pragma unroll
    for (int i = 0; i < 8; ++i) {
      acc[i] += __shfl_xor(acc[i], 16, 64); sq[i] += __shfl_xor(sq[i], 16, 64);
      acc[i] += __shfl_xor(acc[i], 32, 64); sq[i] += __shfl_xor(sq[i], 32, 64);
    }
    if (lane < 16) {
#pragma unroll
      for (int i = 0; i < 8; ++i) { spart[w][cg][i] = acc[i]; spart[w][cg][8 + i] = sq[i]; }
    }
    __syncthreads();
    {
      int ch = tid & 127, half = tid >> 7;
      float v = 0.f;
#pragma unroll
      for (int ww = 0; ww < 4; ++ww) v += spart[ww][ch >> 3][half * 8 + (ch & 7)];
      atomicAdd(&stats1[half * 128 + ch], v);
    }
    return;
  } else {
    // BN1 + relu -> zS
#pragma unroll
    for (int i = 0; i < 8; ++i) {
      int ch = cg * 8 + i;
      float mean = stats1[ch] * inv_m;
      float var = stats1[128 + ch] * inv_m - mean * mean;
      float rs = rsqrtf(var + 1e-5f);
      float zz = (acc[i] - mean) * rs * g1v[ch] + b1v[ch];
      zS[k][ch] = fmaxf(zz, 0.f);
    }
    __syncthreads();
    for (int i = tid; i < 128 * 128; i += 256) bufA[i] = W2[i];
    __syncthreads();
    float u[8];
#pragma unroll
    for (int i = 0; i < 8; ++i) u[i] = 0.f;
    for (int j = 0; j < 128; ++j) {
      float zv = zS[k][j];
      const float4* wp = reinterpret_cast<const float4*>(&bufA[j * 128 + cg * 8]);
      float4 wa = wp[0], wb = wp[1];
      u[0] = fmaf(zv, wa.x, u[0]); u[1] = fmaf(zv, wa.y, u[1]);
      u[2] = fmaf(zv, wa.z, u[2]); u[3] = fmaf(zv, wa.w, u[3]);
      u[4] = fmaf(zv, wb.x, u[4]); u[5] = fmaf(zv, wb.y, u[5]);
      u[6] = fmaf(zv, wb.z, u[6]); u[7] = fmaf(zv, wb.w, u[7]);
    }

    if constexpr (PASS == 1) {
      float sq[8];
#pragma unroll
      for (int i = 0; i < 8; ++i) sq[i] = u[i] * u[i];
#pragma unroll
      for (int i = 0; i < 8; ++i) {
        u[i] += __shfl_xor(u[i], 16, 64); sq[i] += __shfl_xor(sq[i], 16, 64);
        u[i] += __shfl_xor(u[i], 32, 64); sq[i] += __shfl_xor(sq[i], 32, 64);
      }
      if (lane < 16) {
#pragma unroll
        for (int i = 0; i < 8; ++i) { spart[w][cg][i] = u[i]; spart[w][cg][8 + i] = sq[i]; }
      }
      __syncthreads();
      {
        int ch = tid & 127, half = tid >> 7;
        float v = 0.f;
#pragma unroll
        for (int ww = 0; ww < 4; ++ww) v += spart[ww][ch >> 3][half * 8 + (ch & 7)];
        atomicAdd(&stats2[half * 128 + ch], v);
      }
      return;
    } else {
      // BN2 + relu + max over K
      float v8[8];
#pragma unroll
      for (int i = 0; i < 8; ++i) {
        int ch = cg * 8 + i;
        float mean = stats2[ch] * inv_m;
        float var = stats2[128 + ch] * inv_m - mean * mean;
        float rs = rsqrtf(var + 1e-5f);
        float vv = (u[i] - mean) * rs * g2v[ch] + b2v[ch];
        v8[i] = fmaxf(vv, 0.f);
      }
#pragma unroll
      for (int i = 0; i < 8; ++i) {
        v8[i] = fmaxf(v8[i], __shfl_xor(v8[i], 16, 64));
        v8[i] = fmaxf(v8[i], __shfl_xor(v8[i], 32, 64));
      }
      if (lane < 16) {
#pragma unroll
        for (int i = 0; i < 8; ++i) spart[w][cg][i] = v8[i];
      }
      __syncthreads();
      if (tid < 128) {
        int ch = tid;
        float m = spart[0][ch >> 3][ch & 7];
#pragma unroll
        for (int ww = 1; ww < 4; ++ww) m = fmaxf(m, spart[ww][ch >> 3][ch & 7]);
        out_feat[(size_t)bs * 128 + ch] = m;
      }
    }
  }
}

extern "C" void kernel_launch(void* const* d_in, const int* in_sizes, int n_in,
                              void* d_out, int out_size, void* d_ws, size_t ws_size,
                              hipStream_t stream) {
  const float* xyz  = (const float*)d_in[0];
  const float* feat = (const float*)d_in[1];
  const float* W1   = (const float*)d_in[2];
  const float* g1   = (const float*)d_in[3];
  const float* b1   = (const float*)d_in[4];
  const float* W2   = (const float*)d_in[5];
  const float* g2   = (const float*)d_in[6];
  const float* b2   = (const float*)d_in[7];
  float* out = (float*)d_out;
  float* new_xyz = out;                              // [4,2048,3]
  float* out_feat = out + NBATCH * N_SAMP * 3;       // [4,2048,128]

  int* fps_i = (int*)d_ws;                           // [4,2048]
  int* knn_i = fps_i + NBATCH * N_SAMP;              // [4,2048,16]
  float* stats1 = (float*)(knn_i + NBATCH * N_SAMP * KNN_K);  // [256]
  float* stats2 = stats1 + 256;                      // [256]

  hipMemsetAsync(stats1, 0, 512 * sizeof(float), stream);
  hipLaunchKernelGGL(fps_kernel, dim3(NBATCH), dim3(1024), 0, stream, xyz, fps_i, new_xyz);
  hipLaunchKernelGGL(knn_kernel, dim3((NBATCH * N_SAMP) / 4), dim3(256), 0, stream,
                     xyz, new_xyz, knn_i);
  hipLaunchKernelGGL((mlp_kernel<0>), dim3(NBATCH * N_SAMP), dim3(256), 0, stream,
                     xyz, feat, W1, g1, b1, W2, g2, b2, new_xyz, knn_i, stats1, stats2, out_feat);
  hipLaunchKernelGGL((mlp_kernel<1>), dim3(NBATCH * N_SAMP), dim3(256), 0, stream,
                     xyz, feat, W1, g1, b1, W2, g2, b2, new_xyz, knn_i, stats1, stats2, out_feat);
  hipLaunchKernelGGL((mlp_kernel<2>), dim3(NBATCH * N_SAMP), dim3(256), 0, stream,
                     xyz, feat, W1, g1, b1, W2, g2, b2, new_xyz, knn_i, stats1, stats2, out_feat);
}